// Round 6
// baseline (857.373 us; speedup 1.0000x reference)
//
#include <hip/hip_runtime.h>
#include <math.h>

#define H_    16
#define S_    2048
#define MTOK  8192   // B*S

typedef __bf16 bf16_t;
typedef bf16_t bf16x4 __attribute__((ext_vector_type(4)));
typedef bf16_t bf16x8 __attribute__((ext_vector_type(8)));
typedef float  f32x4  __attribute__((ext_vector_type(4)));

__device__ inline f32x4 mfma16(bf16x8 a, bf16x8 b, f32x4 c) {
    return __builtin_amdgcn_mfma_f32_16x16x32_bf16(a, b, c, 0, 0, 0);
}

// async global->LDS, 16B per lane; lds pointer must be wave-uniform
#define GLOAD_LDS(gp, lp)                                                      \
    __builtin_amdgcn_global_load_lds(                                          \
        (const __attribute__((address_space(1))) void*)(gp),                   \
        (__attribute__((address_space(3))) void*)(lp), 16, 0, 0)

// ---------------------------------------------------------------------------
// cast fp32 -> bf16 (n multiple of 4)
// ---------------------------------------------------------------------------
__global__ __launch_bounds__(256) void cast_bf16(const float* __restrict__ in,
                                                 bf16_t* __restrict__ out, int n) {
    const int i = (blockIdx.x * 256 + threadIdx.x) * 4;
    if (i < n) {
        float4 v = *(const float4*)&in[i];
        bf16x4 o = {(bf16_t)v.x, (bf16_t)v.y, (bf16_t)v.z, (bf16_t)v.w};
        *(bf16x4*)&out[i] = o;
    }
}

// ---------------------------------------------------------------------------
// W (KxN fp32) -> Wt (NxK bf16). 32x32 tiles, 256 threads.
// ---------------------------------------------------------------------------
__global__ __launch_bounds__(256) void transpose_cast(const float* __restrict__ W,
                                                      bf16_t* __restrict__ Wt,
                                                      int K, int N) {
    __shared__ float t[32][33];
    const int x = threadIdx.x & 31, y = threadIdx.x >> 5;  // y: 0..7
    const int k0 = blockIdx.y * 32, n0 = blockIdx.x * 32;
#pragma unroll
    for (int j = 0; j < 4; ++j)
        t[y + j * 8][x] = W[(size_t)(k0 + y + j * 8) * N + n0 + x];
    __syncthreads();
#pragma unroll
    for (int j = 0; j < 4; ++j)
        Wt[(size_t)(n0 + y + j * 8) * K + k0 + x] = (bf16_t)t[x][y + j * 8];
}

// ---------------------------------------------------------------------------
// Transposed epilogues (unchanged from R4). Per wave: stage the 64x64 f32
// tile (with bias, EP2: +RoPE) into per-wave LDS T[16][72], then 32B/lane
// writes contiguous in the OUTPUT's fast dimension.
//   EP 0: bf16 row-major (ldc)        EP 1: bf16 (B*H,S,128) col 0..63
//   EP 2: bf16 (B*H,S,128) col 64..127 + RoPE
//   EP 4: bf16 (B*H,S,64)             EP 3: bf16 V^T (B*H,64,S)
//   EP 5: fp32 row-major (ldc), direct (full 64B lines already)
// ---------------------------------------------------------------------------
template <int EP>
__device__ __forceinline__ void ep_store(bf16_t (*__restrict__ T)[72],
                                         void* __restrict__ Cv,
                                         const float* __restrict__ bias,
                                         const f32x4 (&acc)[4][4],
                                         int mbase, int nbl,
                                         int quad, int n16, int ldc) {
    if constexpr (EP == 5) {
        float* C = (float*)Cv;
#pragma unroll
        for (int nt = 0; nt < 4; ++nt) {
            const int nl = nbl + nt * 16 + n16;
            const float bv = bias[nl];
#pragma unroll
            for (int mt = 0; mt < 4; ++mt)
#pragma unroll
                for (int r = 0; r < 4; ++r) {
                    const int m = mbase + mt * 16 + quad * 4 + r;
                    C[(size_t)m * ldc + nl] = acc[mt][nt][r] + bv;
                }
        }
    } else if constexpr (EP == 3) {
        bf16_t* C = (bf16_t*)Cv;
        const int b2 = mbase >> 11, sbase = mbase & 2047;
#pragma unroll
        for (int nt = 0; nt < 4; ++nt) {
            const int nl = nbl + nt * 16 + n16;
            const float bv = bias[nl];
#pragma unroll
            for (int mt = 0; mt < 4; ++mt) {
                bf16x4 o = {(bf16_t)(acc[mt][nt][0] + bv),
                            (bf16_t)(acc[mt][nt][1] + bv),
                            (bf16_t)(acc[mt][nt][2] + bv),
                            (bf16_t)(acc[mt][nt][3] + bv)};
                *(bf16x4*)&T[n16][mt * 16 + quad * 4] = o;  // T[vd][m_local]
            }
            const int h = nl >> 6, vd = nl & 63;
            bf16x8 w0 = *(const bf16x8*)&T[n16][quad * 16];
            bf16x8 w1 = *(const bf16x8*)&T[n16][quad * 16 + 8];
            bf16_t* dst = C + ((size_t)(b2 * H_ + h) * 64 + vd) * S_
                            + sbase + quad * 16;
            *(bf16x8*)dst = w0;
            *(bf16x8*)(dst + 8) = w1;
        }
    } else {
        bf16_t* C = (bf16_t*)Cv;
#pragma unroll
        for (int mt = 0; mt < 4; ++mt) {
#pragma unroll
            for (int nt = 0; nt < 4; ++nt) {
                const int nl = nbl + nt * 16 + n16;
                const float bv = bias[nl];
#pragma unroll
                for (int r = 0; r < 4; ++r) {
                    float v = acc[mt][nt][r] + bv;
                    if constexpr (EP == 2) {
                        const int d = nl & 63;
                        const float fr =
                            exp2f(-(float)(d >> 1) * 0.4152410118609203f);
                        const float sgn = (d & 1) ? 1.0f : -1.0f;
                        const int m = mbase + mt * 16 + quad * 4 + r;
                        const int s = m & 2047;
                        const float vp = __shfl_xor(v, 1);  // partner d^1
                        float sn, cs;
                        sincosf((float)s * fr, &sn, &cs);
                        v = v * cs + sgn * vp * sn;
                    }
                    T[quad * 4 + r][nt * 16 + n16] = (bf16_t)v;  // T[m_loc][n_loc]
                }
            }
            const int m = mbase + mt * 16 + n16;   // n16 = row index on readout
            const int nc = nbl + quad * 16;        // 16-col chunk base
            bf16x8 w0 = *(const bf16x8*)&T[n16][quad * 16];
            bf16x8 w1 = *(const bf16x8*)&T[n16][quad * 16 + 8];
            bf16_t* dst;
            if constexpr (EP == 0) {
                dst = C + (size_t)m * ldc + nc;
            } else {
                const int b2 = m >> 11, s = m & 2047;
                const int h = nc >> 6, c = nc & 63;
                if constexpr (EP == 1)
                    dst = C + ((size_t)(b2 * H_ + h) * S_ + s) * 128 + c;
                else if constexpr (EP == 2)
                    dst = C + ((size_t)(b2 * H_ + h) * S_ + s) * 128 + 64 + c;
                else
                    dst = C + ((size_t)(b2 * H_ + h) * S_ + s) * 64 + c;
            }
            *(bf16x8*)dst = w0;
            *(bf16x8*)(dst + 8) = w1;
        }
    }
}

// ---------------------------------------------------------------------------
// MFMA GEMM: C = A(MxK,bf16) @ Bt(NxK,bf16)^T + bias. 128x128 tile, BK=32,
// 256 thr = 4 waves (2x2), single-buffer staging (R5's dbuf REVERTED:
// A/B FETCH went 383->617MB with it — deeper in-flight window de-cohered
// block timing and thrashed panel reuse; dur got worse too).
// R6: GRID TRANSPOSED — blockIdx.x = m-block, blockIdx.y = n-block.
//   * consecutive hw blocks share the B-panel (weights, small) -> B fetched
//     ~once per XCD (temporally adjacent cohort);
//   * XCD (= bx%8) owns a fixed residue class of m-panels -> per-XCD A-set
//     is 1-4MB, L2-resident across n-phases -> A (the big activation
//     matrix) fetched ~once instead of 8x+.
// Fused along N: cols [0,nsplit) -> EPLO/Clo/bias_lo, rest -> EPHI/Chi.
// nsplit multiple of 64 -> lo/hi split is wave-uniform.
// ---------------------------------------------------------------------------
template <int EPLO, int EPHI>
__global__ __launch_bounds__(256) void mgemm(const bf16_t* __restrict__ A,
                                             const bf16_t* __restrict__ Bt,
                                             const float* __restrict__ bias_lo,
                                             const float* __restrict__ bias_hi,
                                             void* __restrict__ Clo,
                                             void* __restrict__ Chi,
                                             int M, int N, int K, int nsplit, int ldc) {
    __shared__ union ShU {
        struct { bf16_t As[4096]; bf16_t Bs[4096]; } s;  // K-loop staging
        bf16_t Ts[4][16][72];                            // epilogue transpose
    } u;

    const int tid = threadIdx.x;
    const int lane = tid & 63, wave = tid >> 6;
    const int n16 = lane & 15, quad = lane >> 4;
    const int wm = wave & 1, wn = wave >> 1;
    const int m0 = blockIdx.x * 128, n0 = blockIdx.y * 128;   // TRANSPOSED

    const int crow = tid >> 2, ccol = (tid & 3) * 8;
    const bf16_t* Ag0 = A + (size_t)(m0 + crow) * K + ccol;
    const bf16_t* Ag1 = A + (size_t)(m0 + crow + 64) * K + ccol;
    const bf16_t* Bg0 = Bt + (size_t)(n0 + crow) * K + ccol;
    const bf16_t* Bg1 = Bt + (size_t)(n0 + crow + 64) * K + ccol;
    bf16_t* Al0 = u.s.As + wave * 512;
    bf16_t* Al1 = u.s.As + 2048 + wave * 512;
    bf16_t* Bl0 = u.s.Bs + wave * 512;
    bf16_t* Bl1 = u.s.Bs + 2048 + wave * 512;

    f32x4 acc[4][4] = {};

    for (int k0 = 0; k0 < K; k0 += 32) {
        GLOAD_LDS(Ag0 + k0, Al0);
        GLOAD_LDS(Ag1 + k0, Al1);
        GLOAD_LDS(Bg0 + k0, Bl0);
        GLOAD_LDS(Bg1 + k0, Bl1);
        __syncthreads();   // drains global_load_lds (vmcnt0) + protects reads
        bf16x8 af[4], bfr[4];
#pragma unroll
        for (int mt = 0; mt < 4; ++mt)
            af[mt] = *(const bf16x8*)&u.s.As[(wm * 64 + mt * 16 + n16) * 32 + quad * 8];
#pragma unroll
        for (int nt = 0; nt < 4; ++nt)
            bfr[nt] = *(const bf16x8*)&u.s.Bs[(wn * 64 + nt * 16 + n16) * 32 + quad * 8];
        __builtin_amdgcn_s_setprio(1);
#pragma unroll
        for (int mt = 0; mt < 4; ++mt)
#pragma unroll
            for (int nt = 0; nt < 4; ++nt)
                acc[mt][nt] = mfma16(af[mt], bfr[nt], acc[mt][nt]);
        __builtin_amdgcn_s_setprio(0);
        __syncthreads();   // protect LDS overwrite next iter (also guards Ts)
    }

    const int mbase = m0 + wm * 64;
    const int nbase = n0 + wn * 64;
    bf16_t (*T)[72] = u.Ts[wave];
    if (nbase < nsplit)
        ep_store<EPLO>(T, Clo, bias_lo, acc, mbase, nbase, quad, n16, ldc);
    else
        ep_store<EPHI>(T, Chi, bias_hi, acc, mbase, nbase - nsplit, quad, n16, ldc);
}

// ---------------------------------------------------------------------------
// k_r projection, bf16 MFMA: Kr(B,S,64) = rope(Xb @ Wtkr^T + b).
// Head-invariant -> computed ONCE (no 16x broadcast). M-tile 64, grid 128.
// ---------------------------------------------------------------------------
__global__ __launch_bounds__(256) void gemm_kr_mfma(const bf16_t* __restrict__ A,
                                                    const bf16_t* __restrict__ Bt,
                                                    const float* __restrict__ bias,
                                                    bf16_t* __restrict__ Kr) {
    __shared__ bf16_t As[64 * 32];
    __shared__ bf16_t Bs[64 * 32];
    const int tid = threadIdx.x;
    const int lane = tid & 63, wave = tid >> 6;
    const int n16 = lane & 15, quad = lane >> 4;
    const int m0 = blockIdx.x * 64;

    const bf16_t* Ag = A + (size_t)(m0 + (tid >> 2)) * 2048 + (tid & 3) * 8;
    const bf16_t* Bg = Bt + (size_t)(tid >> 2) * 2048 + (tid & 3) * 8;
    bf16_t* Al = As + wave * 512;   // linear: lds_addr = base + lane*16B
    bf16_t* Bl = Bs + wave * 512;

    f32x4 acc[4] = {};
    for (int k0 = 0; k0 < 2048; k0 += 32) {
        GLOAD_LDS(Ag + k0, Al);
        GLOAD_LDS(Bg + k0, Bl);
        __syncthreads();
        bf16x8 af = *(const bf16x8*)&As[(wave * 16 + n16) * 32 + quad * 8];
#pragma unroll
        for (int nt = 0; nt < 4; ++nt) {
            bf16x8 bfr = *(const bf16x8*)&Bs[(nt * 16 + n16) * 32 + quad * 8];
            acc[nt] = mfma16(af, bfr, acc[nt]);
        }
        __syncthreads();
    }
#pragma unroll
    for (int nt = 0; nt < 4; ++nt) {
        const int d = nt * 16 + n16;
        const float bv = bias[d];
        const float fr = exp2f(-(float)(d >> 1) * 0.4152410118609203f);
        const float sgn = (d & 1) ? 1.0f : -1.0f;
#pragma unroll
        for (int r = 0; r < 4; ++r) {
            const int m = m0 + wave * 16 + quad * 4 + r;
            const int b = m >> 11, s = m & 2047;
            const float v = acc[nt][r] + bv;
            const float vp = __shfl_xor(v, 1);
            float sn, cs;
            sincosf((float)s * fr, &sn, &cs);
            Kr[((size_t)(b * S_ + s)) * 64 + d] = (bf16_t)(v * cs + sgn * vp * sn);
        }
    }
}

// ---------------------------------------------------------------------------
// MFMA flash attention (unchanged from R4/R5).
// KVBLK 64, XOR-swizzled Ks, compact Kc+Kr, q-tile pairing, XCD remap
// (flash's per-bh working set is small -> remap HELPS here, unlike mgemm),
// reg-prefetch double-buffer, transposed O-write.
// ---------------------------------------------------------------------------
__global__ __launch_bounds__(256, 4) void flash_mfma(const bf16_t* __restrict__ Q,
                                                     const bf16_t* __restrict__ Kc,
                                                     const bf16_t* __restrict__ Kr,
                                                     const bf16_t* __restrict__ Vt,
                                                     bf16_t* __restrict__ O) {
    __shared__ bf16_t Ks[64 * 128];   // swizzled, row stride 256B
    __shared__ bf16_t Vs[64][72];
    __shared__ bf16_t Ps[4][16][72];

    const int tid  = threadIdx.x;
    const int lane = tid & 63;
    const int wave = tid >> 6;
    const int n16  = lane & 15;
    const int quad = lane >> 4;

    // bijective remap: xcd = flat&7 owns bh in [8*xcd, 8*xcd+8)
    const int flat = blockIdx.x + (blockIdx.y << 4);
    const int bh   = ((flat & 7) << 3) | ((flat >> 3) & 7);
    const int pr   = flat >> 6;          // 0..15 (pair index)
    const int b    = bh >> 4, h = bh & 15;

    const bf16_t* Kcg = Kc + (size_t)bh * S_ * 64;
    const bf16_t* Krg = Kr + (size_t)b * S_ * 64;
    const bf16_t* Vg  = Vt + (size_t)bh * 64 * S_;

    const int srow = tid >> 3;          // 0..31 (+32 on second pass)
    const int scol = (tid & 7) << 3;    // elem col 0..56

    const float scale = 0.051776695296636886f;

    for (int pp = 0; pp < 2; ++pp) {
        const int qt = pp ? (31 - pr) : pr;
        const int q0 = qt << 6;
        const int qbase = q0 + wave * 16;

        const bf16_t* Qg = Q + ((size_t)bh * S_ + qbase + n16) * 128;
        bf16x8 qf[4];
#pragma unroll
        for (int c = 0; c < 4; ++c)
            qf[c] = *(const bf16x8*)(Qg + c * 32 + quad * 8);

        f32x4 oacc[4] = {};
        float mrow[4] = {-3e30f, -3e30f, -3e30f, -3e30f};
        float lrow[4] = {};
        const int ktiles = qt + 1;

        // prologue: prefetch tile 0 into registers
        bf16x8 kc0 = *(const bf16x8*)&Kcg[(size_t)srow * 64 + scol];
        bf16x8 kc1 = *(const bf16x8*)&Kcg[(size_t)(srow + 32) * 64 + scol];
        bf16x8 kr0 = *(const bf16x8*)&Krg[(size_t)srow * 64 + scol];
        bf16x8 kr1 = *(const bf16x8*)&Krg[(size_t)(srow + 32) * 64 + scol];
        bf16x8 v0  = *(const bf16x8*)&Vg[(size_t)srow * S_ + scol];
        bf16x8 v1  = *(const bf16x8*)&Vg[(size_t)(srow + 32) * S_ + scol];

        for (int t = 0; t < ktiles; ++t) {
            const int k0 = t << 6;
            __syncthreads();   // previous compute done -> LDS writable
#define KSP(row, colb) ((bf16_t*)((char*)Ks + ((((row) << 8) + (colb)) ^ (((row) & 7) << 4))))
            *(bf16x8*)KSP(srow, scol * 2)            = kc0;
            *(bf16x8*)KSP(srow + 32, scol * 2)       = kc1;
            *(bf16x8*)KSP(srow, 128 + scol * 2)      = kr0;
            *(bf16x8*)KSP(srow + 32, 128 + scol * 2) = kr1;
            *(bf16x8*)&Vs[srow][scol]      = v0;
            *(bf16x8*)&Vs[srow + 32][scol] = v1;
            if (t + 1 < ktiles) {   // issue next tile's loads now; complete
                const int kn = k0 + 64;  // during this tile's compute
                kc0 = *(const bf16x8*)&Kcg[(size_t)(kn + srow) * 64 + scol];
                kc1 = *(const bf16x8*)&Kcg[(size_t)(kn + srow + 32) * 64 + scol];
                kr0 = *(const bf16x8*)&Krg[(size_t)(kn + srow) * 64 + scol];
                kr1 = *(const bf16x8*)&Krg[(size_t)(kn + srow + 32) * 64 + scol];
                v0  = *(const bf16x8*)&Vg[(size_t)srow * S_ + kn + scol];
                v1  = *(const bf16x8*)&Vg[(size_t)(srow + 32) * S_ + kn + scol];
            }
            __syncthreads();   // LDS visible to all waves

            f32x4 sacc[4] = {};
            __builtin_amdgcn_s_setprio(1);
#pragma unroll
            for (int c = 0; c < 4; ++c) {
#pragma unroll
                for (int j = 0; j < 4; ++j) {
                    bf16x8 kb = *(const bf16x8*)KSP(n16 + 16 * j, c * 64 + quad * 16);
                    sacc[j] = mfma16(qf[c], kb, sacc[j]);
                }
            }
            __builtin_amdgcn_s_setprio(0);

            const bool boundary = (k0 + 63 > qbase);
#pragma unroll
            for (int j = 0; j < 4; ++j)
#pragma unroll
                for (int r = 0; r < 4; ++r) {
                    float s = sacc[j][r] * scale;
                    if (boundary && (k0 + 16 * j + n16 > qbase + quad * 4 + r))
                        s = -3e30f;
                    sacc[j][r] = s;
                }

            float alpha[4];
#pragma unroll
            for (int r = 0; r < 4; ++r) {
                float mx = fmaxf(fmaxf(sacc[0][r], sacc[1][r]),
                                 fmaxf(sacc[2][r], sacc[3][r]));
                mx = fmaxf(mx, __shfl_xor(mx, 1));
                mx = fmaxf(mx, __shfl_xor(mx, 2));
                mx = fmaxf(mx, __shfl_xor(mx, 4));
                mx = fmaxf(mx, __shfl_xor(mx, 8));
                const float mn = fmaxf(mrow[r], mx);
                alpha[r] = __expf(mrow[r] - mn);
                mrow[r] = mn;
                float rs = 0.f;
#pragma unroll
                for (int j = 0; j < 4; ++j) {
                    const float e = __expf(sacc[j][r] - mn);
                    sacc[j][r] = e;
                    rs += e;
                }
                rs += __shfl_xor(rs, 1);
                rs += __shfl_xor(rs, 2);
                rs += __shfl_xor(rs, 4);
                rs += __shfl_xor(rs, 8);
                lrow[r] = lrow[r] * alpha[r] + rs;
            }
#pragma unroll
            for (int nt = 0; nt < 4; ++nt)
#pragma unroll
                for (int r = 0; r < 4; ++r)
                    oacc[nt][r] *= alpha[r];

#pragma unroll
            for (int r = 0; r < 4; ++r)
#pragma unroll
                for (int j = 0; j < 4; ++j)
                    Ps[wave][quad * 4 + r][j * 16 + n16] = (bf16_t)sacc[j][r];

            __builtin_amdgcn_s_setprio(1);
#pragma unroll
            for (int hh = 0; hh < 2; ++hh) {
                bf16x8 pf = *(const bf16x8*)&Ps[wave][n16][hh * 32 + quad * 8];
#pragma unroll
                for (int nt = 0; nt < 4; ++nt) {
                    bf16x8 vb = *(const bf16x8*)&Vs[nt * 16 + n16][hh * 32 + quad * 8];
                    oacc[nt] = mfma16(pf, vb, oacc[nt]);
                }
            }
            __builtin_amdgcn_s_setprio(0);
        }

        float il[4];
#pragma unroll
        for (int r = 0; r < 4; ++r) il[r] = 1.0f / lrow[r];

        // transposed O-write: stage 16q x 64d per wave in Ps, then 32B/lane
        // writes (4 lanes cover a 128B-contiguous output row).
#pragma unroll
        for (int nt = 0; nt < 4; ++nt)
#pragma unroll
            for (int r = 0; r < 4; ++r)
                Ps[wave][quad * 4 + r][nt * 16 + n16] = (bf16_t)(oacc[nt][r] * il[r]);
        {
            const int q = qbase + n16;
            bf16x8 w0 = *(const bf16x8*)&Ps[wave][n16][quad * 16];
            bf16x8 w1 = *(const bf16x8*)&Ps[wave][n16][quad * 16 + 8];
            bf16_t* dst = O + ((size_t)b * S_ + q) * (size_t)(H_ * 64)
                            + h * 64 + quad * 16;
            *(bf16x8*)dst = w0;
            *(bf16x8*)(dst + 8) = w1;
        }
    }
}

// ---------------------------------------------------------------------------
extern "C" void kernel_launch(void* const* d_in, const int* in_sizes, int n_in,
                              void* d_out, int out_size, void* d_ws, size_t ws_size,
                              hipStream_t stream) {
    const float* X     = (const float*)d_in[0];
    const float* W_dkv = (const float*)d_in[2];
    const float* b_dkv = (const float*)d_in[3];
    const float* W_dq  = (const float*)d_in[4];
    const float* b_dq  = (const float*)d_in[5];
    const float* W_uk  = (const float*)d_in[6];
    const float* b_uk  = (const float*)d_in[7];
    const float* W_uv  = (const float*)d_in[8];
    const float* b_uv  = (const float*)d_in[9];
    const float* W_uq  = (const float*)d_in[10];
    const float* b_uq  = (const float*)d_in[11];
    const float* W_qr  = (const float*)d_in[12];
    const float* b_qr  = (const float*)d_in[13];
    const float* W_kr  = (const float*)d_in[14];
    const float* b_kr  = (const float*)d_in[15];
    const float* W_fc  = (const float*)d_in[16];
    const float* b_fc  = (const float*)d_in[17];
    float* out = (float*)d_out;

    char* w = (char*)d_ws;
    bf16_t* Xb    = (bf16_t*)(w);                 // 8192x2048    33,554,432 B
    bf16_t* Wtdkv = (bf16_t*)(w + 33554432);      // 512x2048 (Wtdq adjacent)
    bf16_t* Wtdq  = (bf16_t*)(w + 35651584);      // 512x2048
    bf16_t* Wtuk  = (bf16_t*)(w + 37748736);      // 1024x512 (Wtuv adjacent)
    bf16_t* Wtuv  = (bf16_t*)(w + 38797312);      // 1024x512
    bf16_t* Wtuq  = (bf16_t*)(w + 39845888);      // 1024x512 (Wtqr adjacent)
    bf16_t* Wtqr  = (bf16_t*)(w + 40894464);      // 1024x512
    bf16_t* Wtfc  = (bf16_t*)(w + 41943040);      // 2048x1024     4,194,304
    bf16_t* ckv   = (bf16_t*)(w + 46137344);      // 8192x512 (cq adjacent)
    bf16_t* cq    = (bf16_t*)(w + 54525952);      // 8192x512
    bf16_t* Qb    = (bf16_t*)(w + 62914560);      // (64,2048,128) 33,554,432
    bf16_t* Kc    = (bf16_t*)(w + 96468992);      // (64,2048,64)  16,777,216
    bf16_t* Kr    = (bf16_t*)(w + 113246208);     // (4,2048,64)    1,048,576
    bf16_t* Wtkr  = (bf16_t*)(w + 114294784);     // 64x2048          262,144
    bf16_t* Vt    = (bf16_t*)(w + 130023424);     // (64,64,2048)  16,777,216
    bf16_t* attnb = (bf16_t*)(w + 146800640);     // 8192x1024    16,777,216

    const dim3 blk(256);
    // one-time casts / transposes
    cast_bf16<<<16384, blk, 0, stream>>>(X, Xb, 16777216);
    transpose_cast<<<dim3(16, 64), blk, 0, stream>>>(W_dkv, Wtdkv, 2048, 512);
    transpose_cast<<<dim3(16, 64), blk, 0, stream>>>(W_dq, Wtdq, 2048, 512);
    transpose_cast<<<dim3(32, 16), blk, 0, stream>>>(W_uk, Wtuk, 512, 1024);
    transpose_cast<<<dim3(32, 16), blk, 0, stream>>>(W_uv, Wtuv, 512, 1024);
    transpose_cast<<<dim3(32, 16), blk, 0, stream>>>(W_uq, Wtuq, 512, 1024);
    transpose_cast<<<dim3(32, 16), blk, 0, stream>>>(W_qr, Wtqr, 512, 1024);
    transpose_cast<<<dim3(64, 32), blk, 0, stream>>>(W_fc, Wtfc, 1024, 2048);
    transpose_cast<<<dim3(2, 64), blk, 0, stream>>>(W_kr, Wtkr, 2048, 64);
    // fused projections; TRANSPOSED grids: (m-blocks, n-blocks)
    mgemm<0, 0><<<dim3(64, 8), blk, 0, stream>>>(Xb, Wtdkv, b_dkv, b_dq, ckv, cq,
                                                 MTOK, 1024, 2048, 512, 512);
    mgemm<4, 3><<<dim3(64, 16), blk, 0, stream>>>(ckv, Wtuk, b_uk, b_uv, Kc, Vt,
                                                  MTOK, 2048, 512, 1024, 0);
    mgemm<1, 2><<<dim3(64, 16), blk, 0, stream>>>(cq, Wtuq, b_uq, b_qr, Qb, Qb,
                                                  MTOK, 2048, 512, 1024, 0);
    gemm_kr_mfma<<<dim3(128), blk, 0, stream>>>(Xb, Wtkr, b_kr, Kr);
    // attention + out-proj
    flash_mfma<<<dim3(16, 64), blk, 0, stream>>>(Qb, Kc, Kr, Vt, attnb);
    mgemm<5, 5><<<dim3(64, 16), blk, 0, stream>>>(attnb, Wtfc, b_fc, b_fc, out, out,
                                                  MTOK, 2048, 1024, 2048, 2048);
}

// Round 7
// 828.621 us; speedup vs baseline: 1.0347x; 1.0347x over previous
//
#include <hip/hip_runtime.h>
#include <math.h>

#define H_    16
#define S_    2048
#define MTOK  8192   // B*S

typedef __bf16 bf16_t;
typedef bf16_t bf16x4 __attribute__((ext_vector_type(4)));
typedef bf16_t bf16x8 __attribute__((ext_vector_type(8)));
typedef float  f32x4  __attribute__((ext_vector_type(4)));

__device__ inline f32x4 mfma16(bf16x8 a, bf16x8 b, f32x4 c) {
    return __builtin_amdgcn_mfma_f32_16x16x32_bf16(a, b, c, 0, 0, 0);
}

// async global->LDS, 16B per lane; lds pointer must be wave-uniform
#define GLOAD_LDS(gp, lp)                                                      \
    __builtin_amdgcn_global_load_lds(                                          \
        (const __attribute__((address_space(1))) void*)(gp),                   \
        (__attribute__((address_space(3))) void*)(lp), 16, 0, 0)

// ---------------------------------------------------------------------------
// cast fp32 -> bf16 (n multiple of 4)
// ---------------------------------------------------------------------------
__global__ __launch_bounds__(256) void cast_bf16(const float* __restrict__ in,
                                                 bf16_t* __restrict__ out, int n) {
    const int i = (blockIdx.x * 256 + threadIdx.x) * 4;
    if (i < n) {
        float4 v = *(const float4*)&in[i];
        bf16x4 o = {(bf16_t)v.x, (bf16_t)v.y, (bf16_t)v.z, (bf16_t)v.w};
        *(bf16x4*)&out[i] = o;
    }
}

// ---------------------------------------------------------------------------
// W (KxN fp32) -> Wt (NxK bf16). 32x32 tiles, 256 threads.
// ---------------------------------------------------------------------------
__global__ __launch_bounds__(256) void transpose_cast(const float* __restrict__ W,
                                                      bf16_t* __restrict__ Wt,
                                                      int K, int N) {
    __shared__ float t[32][33];
    const int x = threadIdx.x & 31, y = threadIdx.x >> 5;  // y: 0..7
    const int k0 = blockIdx.y * 32, n0 = blockIdx.x * 32;
#pragma unroll
    for (int j = 0; j < 4; ++j)
        t[y + j * 8][x] = W[(size_t)(k0 + y + j * 8) * N + n0 + x];
    __syncthreads();
#pragma unroll
    for (int j = 0; j < 4; ++j)
        Wt[(size_t)(n0 + y + j * 8) * K + k0 + x] = (bf16_t)t[x][y + j * 8];
}

// ---------------------------------------------------------------------------
// Transposed epilogues (same semantics as R4-R6). Per wave: stage the 64x64
// f32 tile (with bias, EP2: +RoPE) into per-wave LDS T[16][72], then 32B/lane
// writes contiguous in the OUTPUT's fast dimension.
//   EP 0: bf16 row-major (ldc)        EP 1: bf16 (B*H,S,128) col 0..63
//   EP 2: bf16 (B*H,S,128) col 64..127 + RoPE
//   EP 4: bf16 (B*H,S,64)             EP 3: bf16 V^T (B*H,64,S)
//   EP 5: fp32 row-major (ldc), direct (64B chunks)
// ---------------------------------------------------------------------------
template <int EP>
__device__ __forceinline__ void ep_store(bf16_t (*__restrict__ T)[72],
                                         void* __restrict__ Cv,
                                         const float* __restrict__ bias,
                                         const f32x4 (&acc)[4][4],
                                         int mbase, int nbl,
                                         int quad, int n16, int ldc) {
    if constexpr (EP == 5) {
        float* C = (float*)Cv;
#pragma unroll
        for (int nt = 0; nt < 4; ++nt) {
            const int nl = nbl + nt * 16 + n16;
            const float bv = bias[nl];
#pragma unroll
            for (int mt = 0; mt < 4; ++mt)
#pragma unroll
                for (int r = 0; r < 4; ++r) {
                    const int m = mbase + mt * 16 + quad * 4 + r;
                    C[(size_t)m * ldc + nl] = acc[mt][nt][r] + bv;
                }
        }
    } else if constexpr (EP == 3) {
        bf16_t* C = (bf16_t*)Cv;
        const int b2 = mbase >> 11, sbase = mbase & 2047;
#pragma unroll
        for (int nt = 0; nt < 4; ++nt) {
            const int nl = nbl + nt * 16 + n16;
            const float bv = bias[nl];
#pragma unroll
            for (int mt = 0; mt < 4; ++mt) {
                bf16x4 o = {(bf16_t)(acc[mt][nt][0] + bv),
                            (bf16_t)(acc[mt][nt][1] + bv),
                            (bf16_t)(acc[mt][nt][2] + bv),
                            (bf16_t)(acc[mt][nt][3] + bv)};
                *(bf16x4*)&T[n16][mt * 16 + quad * 4] = o;  // T[vd][m_local]
            }
            const int h = nl >> 6, vd = nl & 63;
            bf16x8 w0 = *(const bf16x8*)&T[n16][quad * 16];
            bf16x8 w1 = *(const bf16x8*)&T[n16][quad * 16 + 8];
            bf16_t* dst = C + ((size_t)(b2 * H_ + h) * 64 + vd) * S_
                            + sbase + quad * 16;
            *(bf16x8*)dst = w0;
            *(bf16x8*)(dst + 8) = w1;
        }
    } else {
        bf16_t* C = (bf16_t*)Cv;
#pragma unroll
        for (int mt = 0; mt < 4; ++mt) {
#pragma unroll
            for (int nt = 0; nt < 4; ++nt) {
                const int nl = nbl + nt * 16 + n16;
                const float bv = bias[nl];
#pragma unroll
                for (int r = 0; r < 4; ++r) {
                    float v = acc[mt][nt][r] + bv;
                    if constexpr (EP == 2) {
                        const int d = nl & 63;
                        const float fr =
                            exp2f(-(float)(d >> 1) * 0.4152410118609203f);
                        const float sgn = (d & 1) ? 1.0f : -1.0f;
                        const int m = mbase + mt * 16 + quad * 4 + r;
                        const int s = m & 2047;
                        const float vp = __shfl_xor(v, 1);  // partner d^1
                        float sn, cs;
                        sincosf((float)s * fr, &sn, &cs);
                        v = v * cs + sgn * vp * sn;
                    }
                    T[quad * 4 + r][nt * 16 + n16] = (bf16_t)v;  // T[m_loc][n_loc]
                }
            }
            const int m = mbase + mt * 16 + n16;   // n16 = row index on readout
            const int nc = nbl + quad * 16;        // 16-col chunk base
            bf16x8 w0 = *(const bf16x8*)&T[n16][quad * 16];
            bf16x8 w1 = *(const bf16x8*)&T[n16][quad * 16 + 8];
            bf16_t* dst;
            if constexpr (EP == 0) {
                dst = C + (size_t)m * ldc + nc;
            } else {
                const int b2 = m >> 11, s = m & 2047;
                const int h = nc >> 6, c = nc & 63;
                if constexpr (EP == 1)
                    dst = C + ((size_t)(b2 * H_ + h) * S_ + s) * 128 + c;
                else if constexpr (EP == 2)
                    dst = C + ((size_t)(b2 * H_ + h) * S_ + s) * 128 + 64 + c;
                else
                    dst = C + ((size_t)(b2 * H_ + h) * S_ + s) * 64 + c;
            }
            *(bf16x8*)dst = w0;
            *(bf16x8*)(dst + 8) = w1;
        }
    }
}

// ---------------------------------------------------------------------------
// MFMA GEMM: C = A(MxK,bf16) @ Bt(NxK,bf16)^T + bias. 128x128 tile, BK=32,
// 256 thr = 4 waves (2x2), single-buffer m97-style staging.
// R7:
//  * __launch_bounds__(256, 2): explicit 256-VGPR budget. R4-R6 trace showed
//    VGPR_Count=32 (< the 64 needed for acc alone) + ~1.1GB of writes per
//    dispatch = accumulator spilled to scratch, scratch thrashing L2->HBM.
//    This pins the allocator to keep acc in registers.
//  * LDS union REMOVED (separate Ts) — no aliasing conservatism.
//  * XCD working-set partition: xcd=flat&7 owns a contiguous 1/8 of the
//    m-panels; n varies fastest within the XCD. Per-XCD live panel set
//    2MB(A) + 2-4MB(B) instead of ~64MB (all blocks co-resident => ordering
//    alone can never create reuse; the set must be partitioned).
// Fused along N: cols [0,nsplit) -> EPLO/Clo/bias_lo, rest -> EPHI/Chi.
// nsplit multiple of 64 -> lo/hi split is wave-uniform. gridDim.x%8==0.
// ---------------------------------------------------------------------------
template <int EPLO, int EPHI>
__global__ __launch_bounds__(256, 2) void mgemm(const bf16_t* __restrict__ A,
                                                const bf16_t* __restrict__ Bt,
                                                const float* __restrict__ bias_lo,
                                                const float* __restrict__ bias_hi,
                                                void* __restrict__ Clo,
                                                void* __restrict__ Chi,
                                                int M, int N, int K, int nsplit, int ldc) {
    __shared__ bf16_t As[4096];       // 128 rows x 32 k
    __shared__ bf16_t Bs[4096];       // 128 cols x 32 k
    __shared__ bf16_t Ts[4][16][72];  // per-wave epilogue transpose

    const int tid = threadIdx.x;
    const int lane = tid & 63, wave = tid >> 6;
    const int n16 = lane & 15, quad = lane >> 4;
    const int wm = wave & 1, wn = wave >> 1;

    // XCD partition: grid is (m-blocks=64, n-blocks); HW xcd = flat & 7.
    const int flat = blockIdx.y * gridDim.x + blockIdx.x;
    const int xcd = flat & 7, local = flat >> 3;
    const int nblk = gridDim.y, mchunk = gridDim.x >> 3;
    const int nloc = local % nblk, mloc = local / nblk;   // n fastest
    const int m0 = (xcd * mchunk + mloc) * 128;
    const int n0 = nloc * 128;

    const int crow = tid >> 2, ccol = (tid & 3) * 8;
    const bf16_t* Ag0 = A + (size_t)(m0 + crow) * K + ccol;
    const bf16_t* Ag1 = A + (size_t)(m0 + crow + 64) * K + ccol;
    const bf16_t* Bg0 = Bt + (size_t)(n0 + crow) * K + ccol;
    const bf16_t* Bg1 = Bt + (size_t)(n0 + crow + 64) * K + ccol;
    bf16_t* Al0 = As + wave * 512;
    bf16_t* Al1 = As + 2048 + wave * 512;
    bf16_t* Bl0 = Bs + wave * 512;
    bf16_t* Bl1 = Bs + 2048 + wave * 512;

    f32x4 acc[4][4] = {};

    for (int k0 = 0; k0 < K; k0 += 32) {
        GLOAD_LDS(Ag0 + k0, Al0);
        GLOAD_LDS(Ag1 + k0, Al1);
        GLOAD_LDS(Bg0 + k0, Bl0);
        GLOAD_LDS(Bg1 + k0, Bl1);
        __syncthreads();   // drains global_load_lds (vmcnt0) + protects reads
        bf16x8 af[4], bfr[4];
#pragma unroll
        for (int mt = 0; mt < 4; ++mt)
            af[mt] = *(const bf16x8*)&As[(wm * 64 + mt * 16 + n16) * 32 + quad * 8];
#pragma unroll
        for (int nt = 0; nt < 4; ++nt)
            bfr[nt] = *(const bf16x8*)&Bs[(wn * 64 + nt * 16 + n16) * 32 + quad * 8];
        __builtin_amdgcn_s_setprio(1);
#pragma unroll
        for (int mt = 0; mt < 4; ++mt)
#pragma unroll
            for (int nt = 0; nt < 4; ++nt)
                acc[mt][nt] = mfma16(af[mt], bfr[nt], acc[mt][nt]);
        __builtin_amdgcn_s_setprio(0);
        __syncthreads();   // protect LDS overwrite next iter
    }

    const int mbase = m0 + wm * 64;
    const int nbase = n0 + wn * 64;
    bf16_t (*T)[72] = Ts[wave];
    if (nbase < nsplit)
        ep_store<EPLO>(T, Clo, bias_lo, acc, mbase, nbase, quad, n16, ldc);
    else
        ep_store<EPHI>(T, Chi, bias_hi, acc, mbase, nbase - nsplit, quad, n16, ldc);
}

// ---------------------------------------------------------------------------
// k_r projection, bf16 MFMA: Kr(B,S,64) = rope(Xb @ Wtkr^T + b).
// Head-invariant -> computed ONCE (no 16x broadcast). M-tile 64, grid 128.
// ---------------------------------------------------------------------------
__global__ __launch_bounds__(256) void gemm_kr_mfma(const bf16_t* __restrict__ A,
                                                    const bf16_t* __restrict__ Bt,
                                                    const float* __restrict__ bias,
                                                    bf16_t* __restrict__ Kr) {
    __shared__ bf16_t As[64 * 32];
    __shared__ bf16_t Bs[64 * 32];
    const int tid = threadIdx.x;
    const int lane = tid & 63, wave = tid >> 6;
    const int n16 = lane & 15, quad = lane >> 4;
    const int m0 = blockIdx.x * 64;

    const bf16_t* Ag = A + (size_t)(m0 + (tid >> 2)) * 2048 + (tid & 3) * 8;
    const bf16_t* Bg = Bt + (size_t)(tid >> 2) * 2048 + (tid & 3) * 8;
    bf16_t* Al = As + wave * 512;   // linear: lds_addr = base + lane*16B
    bf16_t* Bl = Bs + wave * 512;

    f32x4 acc[4] = {};
    for (int k0 = 0; k0 < 2048; k0 += 32) {
        GLOAD_LDS(Ag + k0, Al);
        GLOAD_LDS(Bg + k0, Bl);
        __syncthreads();
        bf16x8 af = *(const bf16x8*)&As[(wave * 16 + n16) * 32 + quad * 8];
#pragma unroll
        for (int nt = 0; nt < 4; ++nt) {
            bf16x8 bfr = *(const bf16x8*)&Bs[(nt * 16 + n16) * 32 + quad * 8];
            acc[nt] = mfma16(af, bfr, acc[nt]);
        }
        __syncthreads();
    }
#pragma unroll
    for (int nt = 0; nt < 4; ++nt) {
        const int d = nt * 16 + n16;
        const float bv = bias[d];
        const float fr = exp2f(-(float)(d >> 1) * 0.4152410118609203f);
        const float sgn = (d & 1) ? 1.0f : -1.0f;
#pragma unroll
        for (int r = 0; r < 4; ++r) {
            const int m = m0 + wave * 16 + quad * 4 + r;
            const int b = m >> 11, s = m & 2047;
            const float v = acc[nt][r] + bv;
            const float vp = __shfl_xor(v, 1);
            float sn, cs;
            sincosf((float)s * fr, &sn, &cs);
            Kr[((size_t)(b * S_ + s)) * 64 + d] = (bf16_t)(v * cs + sgn * vp * sn);
        }
    }
}

// ---------------------------------------------------------------------------
// MFMA flash attention (unchanged from R4/R5/R6).
// ---------------------------------------------------------------------------
__global__ __launch_bounds__(256, 4) void flash_mfma(const bf16_t* __restrict__ Q,
                                                     const bf16_t* __restrict__ Kc,
                                                     const bf16_t* __restrict__ Kr,
                                                     const bf16_t* __restrict__ Vt,
                                                     bf16_t* __restrict__ O) {
    __shared__ bf16_t Ks[64 * 128];   // swizzled, row stride 256B
    __shared__ bf16_t Vs[64][72];
    __shared__ bf16_t Ps[4][16][72];

    const int tid  = threadIdx.x;
    const int lane = tid & 63;
    const int wave = tid >> 6;
    const int n16  = lane & 15;
    const int quad = lane >> 4;

    // bijective remap: xcd = flat&7 owns bh in [8*xcd, 8*xcd+8)
    const int flat = blockIdx.x + (blockIdx.y << 4);
    const int bh   = ((flat & 7) << 3) | ((flat >> 3) & 7);
    const int pr   = flat >> 6;          // 0..15 (pair index)
    const int b    = bh >> 4, h = bh & 15;

    const bf16_t* Kcg = Kc + (size_t)bh * S_ * 64;
    const bf16_t* Krg = Kr + (size_t)b * S_ * 64;
    const bf16_t* Vg  = Vt + (size_t)bh * 64 * S_;

    const int srow = tid >> 3;          // 0..31 (+32 on second pass)
    const int scol = (tid & 7) << 3;    // elem col 0..56

    const float scale = 0.051776695296636886f;

    for (int pp = 0; pp < 2; ++pp) {
        const int qt = pp ? (31 - pr) : pr;
        const int q0 = qt << 6;
        const int qbase = q0 + wave * 16;

        const bf16_t* Qg = Q + ((size_t)bh * S_ + qbase + n16) * 128;
        bf16x8 qf[4];
#pragma unroll
        for (int c = 0; c < 4; ++c)
            qf[c] = *(const bf16x8*)(Qg + c * 32 + quad * 8);

        f32x4 oacc[4] = {};
        float mrow[4] = {-3e30f, -3e30f, -3e30f, -3e30f};
        float lrow[4] = {};
        const int ktiles = qt + 1;

        // prologue: prefetch tile 0 into registers
        bf16x8 kc0 = *(const bf16x8*)&Kcg[(size_t)srow * 64 + scol];
        bf16x8 kc1 = *(const bf16x8*)&Kcg[(size_t)(srow + 32) * 64 + scol];
        bf16x8 kr0 = *(const bf16x8*)&Krg[(size_t)srow * 64 + scol];
        bf16x8 kr1 = *(const bf16x8*)&Krg[(size_t)(srow + 32) * 64 + scol];
        bf16x8 v0  = *(const bf16x8*)&Vg[(size_t)srow * S_ + scol];
        bf16x8 v1  = *(const bf16x8*)&Vg[(size_t)(srow + 32) * S_ + scol];

        for (int t = 0; t < ktiles; ++t) {
            const int k0 = t << 6;
            __syncthreads();   // previous compute done -> LDS writable
#define KSP(row, colb) ((bf16_t*)((char*)Ks + ((((row) << 8) + (colb)) ^ (((row) & 7) << 4))))
            *(bf16x8*)KSP(srow, scol * 2)            = kc0;
            *(bf16x8*)KSP(srow + 32, scol * 2)       = kc1;
            *(bf16x8*)KSP(srow, 128 + scol * 2)      = kr0;
            *(bf16x8*)KSP(srow + 32, 128 + scol * 2) = kr1;
            *(bf16x8*)&Vs[srow][scol]      = v0;
            *(bf16x8*)&Vs[srow + 32][scol] = v1;
            if (t + 1 < ktiles) {   // issue next tile's loads now; complete
                const int kn = k0 + 64;  // during this tile's compute
                kc0 = *(const bf16x8*)&Kcg[(size_t)(kn + srow) * 64 + scol];
                kc1 = *(const bf16x8*)&Kcg[(size_t)(kn + srow + 32) * 64 + scol];
                kr0 = *(const bf16x8*)&Krg[(size_t)(kn + srow) * 64 + scol];
                kr1 = *(const bf16x8*)&Krg[(size_t)(kn + srow + 32) * 64 + scol];
                v0  = *(const bf16x8*)&Vg[(size_t)srow * S_ + kn + scol];
                v1  = *(const bf16x8*)&Vg[(size_t)(srow + 32) * S_ + kn + scol];
            }
            __syncthreads();   // LDS visible to all waves

            f32x4 sacc[4] = {};
            __builtin_amdgcn_s_setprio(1);
#pragma unroll
            for (int c = 0; c < 4; ++c) {
#pragma unroll
                for (int j = 0; j < 4; ++j) {
                    bf16x8 kb = *(const bf16x8*)KSP(n16 + 16 * j, c * 64 + quad * 16);
                    sacc[j] = mfma16(qf[c], kb, sacc[j]);
                }
            }
            __builtin_amdgcn_s_setprio(0);

            const bool boundary = (k0 + 63 > qbase);
#pragma unroll
            for (int j = 0; j < 4; ++j)
#pragma unroll
                for (int r = 0; r < 4; ++r) {
                    float s = sacc[j][r] * scale;
                    if (boundary && (k0 + 16 * j + n16 > qbase + quad * 4 + r))
                        s = -3e30f;
                    sacc[j][r] = s;
                }

            float alpha[4];
#pragma unroll
            for (int r = 0; r < 4; ++r) {
                float mx = fmaxf(fmaxf(sacc[0][r], sacc[1][r]),
                                 fmaxf(sacc[2][r], sacc[3][r]));
                mx = fmaxf(mx, __shfl_xor(mx, 1));
                mx = fmaxf(mx, __shfl_xor(mx, 2));
                mx = fmaxf(mx, __shfl_xor(mx, 4));
                mx = fmaxf(mx, __shfl_xor(mx, 8));
                const float mn = fmaxf(mrow[r], mx);
                alpha[r] = __expf(mrow[r] - mn);
                mrow[r] = mn;
                float rs = 0.f;
#pragma unroll
                for (int j = 0; j < 4; ++j) {
                    const float e = __expf(sacc[j][r] - mn);
                    sacc[j][r] = e;
                    rs += e;
                }
                rs += __shfl_xor(rs, 1);
                rs += __shfl_xor(rs, 2);
                rs += __shfl_xor(rs, 4);
                rs += __shfl_xor(rs, 8);
                lrow[r] = lrow[r] * alpha[r] + rs;
            }
#pragma unroll
            for (int nt = 0; nt < 4; ++nt)
#pragma unroll
                for (int r = 0; r < 4; ++r)
                    oacc[nt][r] *= alpha[r];

#pragma unroll
            for (int r = 0; r < 4; ++r)
#pragma unroll
                for (int j = 0; j < 4; ++j)
                    Ps[wave][quad * 4 + r][j * 16 + n16] = (bf16_t)sacc[j][r];

            __builtin_amdgcn_s_setprio(1);
#pragma unroll
            for (int hh = 0; hh < 2; ++hh) {
                bf16x8 pf = *(const bf16x8*)&Ps[wave][n16][hh * 32 + quad * 8];
#pragma unroll
                for (int nt = 0; nt < 4; ++nt) {
                    bf16x8 vb = *(const bf16x8*)&Vs[nt * 16 + n16][hh * 32 + quad * 8];
                    oacc[nt] = mfma16(pf, vb, oacc[nt]);
                }
            }
            __builtin_amdgcn_s_setprio(0);
        }

        float il[4];
#pragma unroll
        for (int r = 0; r < 4; ++r) il[r] = 1.0f / lrow[r];

        // transposed O-write: stage 16q x 64d per wave in Ps, then 32B/lane
        // writes (4 lanes cover a 128B-contiguous output row).
#pragma unroll
        for (int nt = 0; nt < 4; ++nt)
#pragma unroll
            for (int r = 0; r < 4; ++r)
                Ps[wave][quad * 4 + r][nt * 16 + n16] = (bf16_t)(oacc[nt][r] * il[r]);
        {
            const int q = qbase + n16;
            bf16x8 w0 = *(const bf16x8*)&Ps[wave][n16][quad * 16];
            bf16x8 w1 = *(const bf16x8*)&Ps[wave][n16][quad * 16 + 8];
            bf16_t* dst = O + ((size_t)b * S_ + q) * (size_t)(H_ * 64)
                            + h * 64 + quad * 16;
            *(bf16x8*)dst = w0;
            *(bf16x8*)(dst + 8) = w1;
        }
    }
}

// ---------------------------------------------------------------------------
extern "C" void kernel_launch(void* const* d_in, const int* in_sizes, int n_in,
                              void* d_out, int out_size, void* d_ws, size_t ws_size,
                              hipStream_t stream) {
    const float* X     = (const float*)d_in[0];
    const float* W_dkv = (const float*)d_in[2];
    const float* b_dkv = (const float*)d_in[3];
    const float* W_dq  = (const float*)d_in[4];
    const float* b_dq  = (const float*)d_in[5];
    const float* W_uk  = (const float*)d_in[6];
    const float* b_uk  = (const float*)d_in[7];
    const float* W_uv  = (const float*)d_in[8];
    const float* b_uv  = (const float*)d_in[9];
    const float* W_uq  = (const float*)d_in[10];
    const float* b_uq  = (const float*)d_in[11];
    const float* W_qr  = (const float*)d_in[12];
    const float* b_qr  = (const float*)d_in[13];
    const float* W_kr  = (const float*)d_in[14];
    const float* b_kr  = (const float*)d_in[15];
    const float* W_fc  = (const float*)d_in[16];
    const float* b_fc  = (const float*)d_in[17];
    float* out = (float*)d_out;

    char* w = (char*)d_ws;
    bf16_t* Xb    = (bf16_t*)(w);                 // 8192x2048    33,554,432 B
    bf16_t* Wtdkv = (bf16_t*)(w + 33554432);      // 512x2048 (Wtdq adjacent)
    bf16_t* Wtdq  = (bf16_t*)(w + 35651584);      // 512x2048
    bf16_t* Wtuk  = (bf16_t*)(w + 37748736);      // 1024x512 (Wtuv adjacent)
    bf16_t* Wtuv  = (bf16_t*)(w + 38797312);      // 1024x512
    bf16_t* Wtuq  = (bf16_t*)(w + 39845888);      // 1024x512 (Wtqr adjacent)
    bf16_t* Wtqr  = (bf16_t*)(w + 40894464);      // 1024x512
    bf16_t* Wtfc  = (bf16_t*)(w + 41943040);      // 2048x1024     4,194,304
    bf16_t* ckv   = (bf16_t*)(w + 46137344);      // 8192x512 (cq adjacent)
    bf16_t* cq    = (bf16_t*)(w + 54525952);      // 8192x512
    bf16_t* Qb    = (bf16_t*)(w + 62914560);      // (64,2048,128) 33,554,432
    bf16_t* Kc    = (bf16_t*)(w + 96468992);      // (64,2048,64)  16,777,216
    bf16_t* Kr    = (bf16_t*)(w + 113246208);     // (4,2048,64)    1,048,576
    bf16_t* Wtkr  = (bf16_t*)(w + 114294784);     // 64x2048          262,144
    bf16_t* Vt    = (bf16_t*)(w + 130023424);     // (64,64,2048)  16,777,216
    bf16_t* attnb = (bf16_t*)(w + 146800640);     // 8192x1024    16,777,216

    const dim3 blk(256);
    // one-time casts / transposes
    cast_bf16<<<16384, blk, 0, stream>>>(X, Xb, 16777216);
    transpose_cast<<<dim3(16, 64), blk, 0, stream>>>(W_dkv, Wtdkv, 2048, 512);
    transpose_cast<<<dim3(16, 64), blk, 0, stream>>>(W_dq, Wtdq, 2048, 512);
    transpose_cast<<<dim3(32, 16), blk, 0, stream>>>(W_uk, Wtuk, 512, 1024);
    transpose_cast<<<dim3(32, 16), blk, 0, stream>>>(W_uv, Wtuv, 512, 1024);
    transpose_cast<<<dim3(32, 16), blk, 0, stream>>>(W_uq, Wtuq, 512, 1024);
    transpose_cast<<<dim3(32, 16), blk, 0, stream>>>(W_qr, Wtqr, 512, 1024);
    transpose_cast<<<dim3(64, 32), blk, 0, stream>>>(W_fc, Wtfc, 1024, 2048);
    transpose_cast<<<dim3(2, 64), blk, 0, stream>>>(W_kr, Wtkr, 2048, 64);
    // fused projections; grids (m-blocks=64, n-blocks)
    mgemm<0, 0><<<dim3(64, 8), blk, 0, stream>>>(Xb, Wtdkv, b_dkv, b_dq, ckv, cq,
                                                 MTOK, 1024, 2048, 512, 512);
    mgemm<4, 3><<<dim3(64, 16), blk, 0, stream>>>(ckv, Wtuk, b_uk, b_uv, Kc, Vt,
                                                  MTOK, 2048, 512, 1024, 0);
    mgemm<1, 2><<<dim3(64, 16), blk, 0, stream>>>(cq, Wtuq, b_uq, b_qr, Qb, Qb,
                                                  MTOK, 2048, 512, 1024, 0);
    gemm_kr_mfma<<<dim3(128), blk, 0, stream>>>(Xb, Wtkr, b_kr, Kr);
    // attention + out-proj
    flash_mfma<<<dim3(16, 64), blk, 0, stream>>>(Qb, Kc, Kr, Vt, attnb);
    mgemm<5, 5><<<dim3(64, 16), blk, 0, stream>>>(attnb, Wtfc, b_fc, b_fc, out, out,
                                                  MTOK, 2048, 1024, 2048, 2048);
}

// Round 8
// 594.572 us; speedup vs baseline: 1.4420x; 1.3936x over previous
//
#include <hip/hip_runtime.h>
#include <math.h>

#define H_    16
#define S_    2048
#define MTOK  8192   // B*S

typedef __bf16 bf16_t;
typedef bf16_t bf16x4 __attribute__((ext_vector_type(4)));
typedef bf16_t bf16x8 __attribute__((ext_vector_type(8)));
typedef float  f32x4  __attribute__((ext_vector_type(4)));

__device__ inline f32x4 mfma16(bf16x8 a, bf16x8 b, f32x4 c) {
    return __builtin_amdgcn_mfma_f32_16x16x32_bf16(a, b, c, 0, 0, 0);
}

// async global->LDS, 16B per lane; lds pointer must be wave-uniform
#define GLOAD_LDS(gp, lp)                                                      \
    __builtin_amdgcn_global_load_lds(                                          \
        (const __attribute__((address_space(1))) void*)(gp),                   \
        (__attribute__((address_space(3))) void*)(lp), 16, 0, 0)

// ---------------------------------------------------------------------------
// cast fp32 -> bf16 (n multiple of 4)
// ---------------------------------------------------------------------------
__global__ __launch_bounds__(256) void cast_bf16(const float* __restrict__ in,
                                                 bf16_t* __restrict__ out, int n) {
    const int i = (blockIdx.x * 256 + threadIdx.x) * 4;
    if (i < n) {
        float4 v = *(const float4*)&in[i];
        bf16x4 o = {(bf16_t)v.x, (bf16_t)v.y, (bf16_t)v.z, (bf16_t)v.w};
        *(bf16x4*)&out[i] = o;
    }
}

// ---------------------------------------------------------------------------
// W (KxN fp32) -> Wt (NxK bf16). 32x32 tiles, 256 threads.
// ---------------------------------------------------------------------------
__global__ __launch_bounds__(256) void transpose_cast(const float* __restrict__ W,
                                                      bf16_t* __restrict__ Wt,
                                                      int K, int N) {
    __shared__ float t[32][33];
    const int x = threadIdx.x & 31, y = threadIdx.x >> 5;  // y: 0..7
    const int k0 = blockIdx.y * 32, n0 = blockIdx.x * 32;
#pragma unroll
    for (int j = 0; j < 4; ++j)
        t[y + j * 8][x] = W[(size_t)(k0 + y + j * 8) * N + n0 + x];
    __syncthreads();
#pragma unroll
    for (int j = 0; j < 4; ++j)
        Wt[(size_t)(n0 + y + j * 8) * K + k0 + x] = (bf16_t)t[x][y + j * 8];
}

// ---------------------------------------------------------------------------
// Transposed epilogues, generalized to MTT m-groups (16 rows each) x 4
// nt-groups (64 cols). Same write patterns as R4-R7 (all passing).
//   EP 0: bf16 row-major (ldc)        EP 1: bf16 (B*H,S,128) col 0..63
//   EP 2: bf16 (B*H,S,128) col 64..127 + RoPE
//   EP 4: bf16 (B*H,S,64)             EP 3: bf16 V^T (B*H,64,S)  [MTT==4]
//   EP 5: fp32 row-major (ldc), direct
// ---------------------------------------------------------------------------
template <int EP, int MTT>
__device__ __forceinline__ void ep_store(bf16_t (*__restrict__ T)[72],
                                         void* __restrict__ Cv,
                                         const float* __restrict__ bias,
                                         const f32x4 (&acc)[MTT][4],
                                         int mbase, int nbl,
                                         int quad, int n16, int ldc) {
    if constexpr (EP == 5) {
        float* C = (float*)Cv;
#pragma unroll
        for (int nt = 0; nt < 4; ++nt) {
            const int nl = nbl + nt * 16 + n16;
            const float bv = bias[nl];
#pragma unroll
            for (int mt = 0; mt < MTT; ++mt)
#pragma unroll
                for (int r = 0; r < 4; ++r) {
                    const int m = mbase + mt * 16 + quad * 4 + r;
                    C[(size_t)m * ldc + nl] = acc[mt][nt][r] + bv;
                }
        }
    } else if constexpr (EP == 3) {
        // requires MTT == 4 (64 m-cols staged per vd row)
        bf16_t* C = (bf16_t*)Cv;
        const int b2 = mbase >> 11, sbase = mbase & 2047;
#pragma unroll
        for (int nt = 0; nt < 4; ++nt) {
            const int nl = nbl + nt * 16 + n16;
            const float bv = bias[nl];
#pragma unroll
            for (int mt = 0; mt < MTT; ++mt) {
                bf16x4 o = {(bf16_t)(acc[mt][nt][0] + bv),
                            (bf16_t)(acc[mt][nt][1] + bv),
                            (bf16_t)(acc[mt][nt][2] + bv),
                            (bf16_t)(acc[mt][nt][3] + bv)};
                *(bf16x4*)&T[n16][mt * 16 + quad * 4] = o;  // T[vd][m_local]
            }
            const int h = nl >> 6, vd = nl & 63;
            bf16x8 w0 = *(const bf16x8*)&T[n16][quad * 16];
            bf16x8 w1 = *(const bf16x8*)&T[n16][quad * 16 + 8];
            bf16_t* dst = C + ((size_t)(b2 * H_ + h) * 64 + vd) * S_
                            + sbase + quad * 16;
            *(bf16x8*)dst = w0;
            *(bf16x8*)(dst + 8) = w1;
        }
    } else {
        bf16_t* C = (bf16_t*)Cv;
#pragma unroll
        for (int mt = 0; mt < MTT; ++mt) {
#pragma unroll
            for (int nt = 0; nt < 4; ++nt) {
                const int nl = nbl + nt * 16 + n16;
                const float bv = bias[nl];
#pragma unroll
                for (int r = 0; r < 4; ++r) {
                    float v = acc[mt][nt][r] + bv;
                    if constexpr (EP == 2) {
                        const int d = nl & 63;
                        const float fr =
                            exp2f(-(float)(d >> 1) * 0.4152410118609203f);
                        const float sgn = (d & 1) ? 1.0f : -1.0f;
                        const int m = mbase + mt * 16 + quad * 4 + r;
                        const int s = m & 2047;
                        const float vp = __shfl_xor(v, 1);  // partner d^1
                        float sn, cs;
                        sincosf((float)s * fr, &sn, &cs);
                        v = v * cs + sgn * vp * sn;
                    }
                    T[quad * 4 + r][nt * 16 + n16] = (bf16_t)v;  // T[m_loc][n_loc]
                }
            }
            const int m = mbase + mt * 16 + n16;   // n16 = row index on readout
            const int nc = nbl + quad * 16;        // 16-col chunk base
            bf16x8 w0 = *(const bf16x8*)&T[n16][quad * 16];
            bf16x8 w1 = *(const bf16x8*)&T[n16][quad * 16 + 8];
            bf16_t* dst;
            if constexpr (EP == 0) {
                dst = C + (size_t)m * ldc + nc;
            } else {
                const int b2 = m >> 11, s = m & 2047;
                const int h = nc >> 6, c = nc & 63;
                if constexpr (EP == 1)
                    dst = C + ((size_t)(b2 * H_ + h) * S_ + s) * 128 + c;
                else if constexpr (EP == 2)
                    dst = C + ((size_t)(b2 * H_ + h) * S_ + s) * 128 + 64 + c;
                else
                    dst = C + ((size_t)(b2 * H_ + h) * S_ + s) * 64 + c;
            }
            *(bf16x8*)dst = w0;
            *(bf16x8*)(dst + 8) = w1;
        }
    }
}

// ---------------------------------------------------------------------------
// 512-thread 8-wave MFMA GEMM: C = A(MxK) @ Bt(NxK)^T + bias.
// BM = WM*MT*16, BN = WN*NT*16, BK = 32.
// R8 rationale: the 128^2 tile's refetch bound (N/BN)|A| + (M/BM)|B| = 536MB
// matched measured FETCH exactly (zero L2 reuse; whole grid co-resident =>
// ordering can never create reuse). Bigger tiles are the only lever:
//   256x256 (mg43/mg12/mg55): FETCH bound 536 -> 268MB, grid 256 = 1/CU.
//   128x256 (mg00, N=1024):   FETCH bound 536 -> 402MB, grid 256 = 1/CU.
// Same proven fragment math / staging / epilogues as the 128^2 kernel.
// Fused along N: each 64-col chunk goes lo/hi by nsplit (multiple of 64).
// ---------------------------------------------------------------------------
template <int EPLO, int EPHI, int WM, int WN, int MT, int NT>
__global__ __launch_bounds__(512, 1) void mgemm2(const bf16_t* __restrict__ A,
                                                 const bf16_t* __restrict__ Bt,
                                                 const float* __restrict__ bias_lo,
                                                 const float* __restrict__ bias_hi,
                                                 void* __restrict__ Clo,
                                                 void* __restrict__ Chi,
                                                 int M, int N, int K,
                                                 int nsplit, int ldc) {
    constexpr int BM = WM * MT * 16;
    constexpr int BN = WN * NT * 16;
    constexpr int RA = BM / 128;   // A staging rounds (512 thr = 128 rows/round)
    constexpr int RB = BN / 128;   // B staging rounds

    __shared__ bf16_t As[BM * 32];
    __shared__ bf16_t Bs[BN * 32];
    __shared__ bf16_t Ts[8][16][72];

    const int tid = threadIdx.x;
    const int lane = tid & 63, wave = tid >> 6;       // wave 0..7
    const int n16 = lane & 15, quad = lane >> 4;
    const int wm = wave & (WM - 1), wn = wave / WM;
    const int m0 = blockIdx.x * BM, n0 = blockIdx.y * BN;

    const int crow = tid >> 2, ccol = (tid & 3) * 8;  // 128 rows x 32 cols

    f32x4 acc[MT][NT] = {};

    for (int k0 = 0; k0 < K; k0 += 32) {
#pragma unroll
        for (int r = 0; r < RA; ++r)
            GLOAD_LDS(A + (size_t)(m0 + r * 128 + crow) * K + ccol + k0,
                      As + r * 4096 + wave * 512);
#pragma unroll
        for (int r = 0; r < RB; ++r)
            GLOAD_LDS(Bt + (size_t)(n0 + r * 128 + crow) * K + ccol + k0,
                      Bs + r * 4096 + wave * 512);
        __syncthreads();   // drains global_load_lds + protects reads
        bf16x8 af[MT], bfr[NT];
#pragma unroll
        for (int mt = 0; mt < MT; ++mt)
            af[mt] = *(const bf16x8*)&As[(wm * MT * 16 + mt * 16 + n16) * 32 + quad * 8];
#pragma unroll
        for (int nt = 0; nt < NT; ++nt)
            bfr[nt] = *(const bf16x8*)&Bs[(wn * NT * 16 + nt * 16 + n16) * 32 + quad * 8];
        __builtin_amdgcn_s_setprio(1);
#pragma unroll
        for (int mt = 0; mt < MT; ++mt)
#pragma unroll
            for (int nt = 0; nt < NT; ++nt)
                acc[mt][nt] = mfma16(af[mt], bfr[nt], acc[mt][nt]);
        __builtin_amdgcn_s_setprio(0);
        __syncthreads();   // protect LDS overwrite next iter
    }

    // epilogue: per wave, (MT/MTT) m-chunks x (NT/4) n-chunks of <=64x64
    constexpr int MTT = (MT < 4) ? MT : 4;
    const int mwave = m0 + wm * MT * 16;
    const int nwave = n0 + wn * NT * 16;
    bf16_t (*T)[72] = Ts[wave];
#pragma unroll
    for (int nch = 0; nch < NT / 4; ++nch) {
#pragma unroll
        for (int mch = 0; mch < MT / MTT; ++mch) {
            f32x4 a2[MTT][4];
#pragma unroll
            for (int i = 0; i < MTT; ++i)
#pragma unroll
                for (int j = 0; j < 4; ++j)
                    a2[i][j] = acc[mch * MTT + i][nch * 4 + j];
            const int mb = mwave + mch * MTT * 16;
            const int nb = nwave + nch * 64;
            if (nb < nsplit)
                ep_store<EPLO, MTT>(T, Clo, bias_lo, a2, mb, nb, quad, n16, ldc);
            else
                ep_store<EPHI, MTT>(T, Chi, bias_hi, a2, mb, nb - nsplit,
                                    quad, n16, ldc);
        }
    }
}

// ---------------------------------------------------------------------------
// k_r projection, bf16 MFMA: Kr(B,S,64) = rope(Xb @ Wtkr^T + b).
// Head-invariant -> computed ONCE (no 16x broadcast). M-tile 64, grid 128.
// ---------------------------------------------------------------------------
__global__ __launch_bounds__(256) void gemm_kr_mfma(const bf16_t* __restrict__ A,
                                                    const bf16_t* __restrict__ Bt,
                                                    const float* __restrict__ bias,
                                                    bf16_t* __restrict__ Kr) {
    __shared__ bf16_t As[64 * 32];
    __shared__ bf16_t Bs[64 * 32];
    const int tid = threadIdx.x;
    const int lane = tid & 63, wave = tid >> 6;
    const int n16 = lane & 15, quad = lane >> 4;
    const int m0 = blockIdx.x * 64;

    const bf16_t* Ag = A + (size_t)(m0 + (tid >> 2)) * 2048 + (tid & 3) * 8;
    const bf16_t* Bg = Bt + (size_t)(tid >> 2) * 2048 + (tid & 3) * 8;
    bf16_t* Al = As + wave * 512;   // linear: lds_addr = base + lane*16B
    bf16_t* Bl = Bs + wave * 512;

    f32x4 acc[4] = {};
    for (int k0 = 0; k0 < 2048; k0 += 32) {
        GLOAD_LDS(Ag + k0, Al);
        GLOAD_LDS(Bg + k0, Bl);
        __syncthreads();
        bf16x8 af = *(const bf16x8*)&As[(wave * 16 + n16) * 32 + quad * 8];
#pragma unroll
        for (int nt = 0; nt < 4; ++nt) {
            bf16x8 bfr = *(const bf16x8*)&Bs[(nt * 16 + n16) * 32 + quad * 8];
            acc[nt] = mfma16(af, bfr, acc[nt]);
        }
        __syncthreads();
    }
#pragma unroll
    for (int nt = 0; nt < 4; ++nt) {
        const int d = nt * 16 + n16;
        const float bv = bias[d];
        const float fr = exp2f(-(float)(d >> 1) * 0.4152410118609203f);
        const float sgn = (d & 1) ? 1.0f : -1.0f;
#pragma unroll
        for (int r = 0; r < 4; ++r) {
            const int m = m0 + wave * 16 + quad * 4 + r;
            const int b = m >> 11, s = m & 2047;
            const float v = acc[nt][r] + bv;
            const float vp = __shfl_xor(v, 1);
            float sn, cs;
            sincosf((float)s * fr, &sn, &cs);
            Kr[((size_t)(b * S_ + s)) * 64 + d] = (bf16_t)(v * cs + sgn * vp * sn);
        }
    }
}

// ---------------------------------------------------------------------------
// MFMA flash attention (unchanged from R4-R7).
// ---------------------------------------------------------------------------
__global__ __launch_bounds__(256, 4) void flash_mfma(const bf16_t* __restrict__ Q,
                                                     const bf16_t* __restrict__ Kc,
                                                     const bf16_t* __restrict__ Kr,
                                                     const bf16_t* __restrict__ Vt,
                                                     bf16_t* __restrict__ O) {
    __shared__ bf16_t Ks[64 * 128];   // swizzled, row stride 256B
    __shared__ bf16_t Vs[64][72];
    __shared__ bf16_t Ps[4][16][72];

    const int tid  = threadIdx.x;
    const int lane = tid & 63;
    const int wave = tid >> 6;
    const int n16  = lane & 15;
    const int quad = lane >> 4;

    // bijective remap: xcd = flat&7 owns bh in [8*xcd, 8*xcd+8)
    const int flat = blockIdx.x + (blockIdx.y << 4);
    const int bh   = ((flat & 7) << 3) | ((flat >> 3) & 7);
    const int pr   = flat >> 6;          // 0..15 (pair index)
    const int b    = bh >> 4, h = bh & 15;

    const bf16_t* Kcg = Kc + (size_t)bh * S_ * 64;
    const bf16_t* Krg = Kr + (size_t)b * S_ * 64;
    const bf16_t* Vg  = Vt + (size_t)bh * 64 * S_;

    const int srow = tid >> 3;          // 0..31 (+32 on second pass)
    const int scol = (tid & 7) << 3;    // elem col 0..56

    const float scale = 0.051776695296636886f;

    for (int pp = 0; pp < 2; ++pp) {
        const int qt = pp ? (31 - pr) : pr;
        const int q0 = qt << 6;
        const int qbase = q0 + wave * 16;

        const bf16_t* Qg = Q + ((size_t)bh * S_ + qbase + n16) * 128;
        bf16x8 qf[4];
#pragma unroll
        for (int c = 0; c < 4; ++c)
            qf[c] = *(const bf16x8*)(Qg + c * 32 + quad * 8);

        f32x4 oacc[4] = {};
        float mrow[4] = {-3e30f, -3e30f, -3e30f, -3e30f};
        float lrow[4] = {};
        const int ktiles = qt + 1;

        // prologue: prefetch tile 0 into registers
        bf16x8 kc0 = *(const bf16x8*)&Kcg[(size_t)srow * 64 + scol];
        bf16x8 kc1 = *(const bf16x8*)&Kcg[(size_t)(srow + 32) * 64 + scol];
        bf16x8 kr0 = *(const bf16x8*)&Krg[(size_t)srow * 64 + scol];
        bf16x8 kr1 = *(const bf16x8*)&Krg[(size_t)(srow + 32) * 64 + scol];
        bf16x8 v0  = *(const bf16x8*)&Vg[(size_t)srow * S_ + scol];
        bf16x8 v1  = *(const bf16x8*)&Vg[(size_t)(srow + 32) * S_ + scol];

        for (int t = 0; t < ktiles; ++t) {
            const int k0 = t << 6;
            __syncthreads();   // previous compute done -> LDS writable
#define KSP(row, colb) ((bf16_t*)((char*)Ks + ((((row) << 8) + (colb)) ^ (((row) & 7) << 4))))
            *(bf16x8*)KSP(srow, scol * 2)            = kc0;
            *(bf16x8*)KSP(srow + 32, scol * 2)       = kc1;
            *(bf16x8*)KSP(srow, 128 + scol * 2)      = kr0;
            *(bf16x8*)KSP(srow + 32, 128 + scol * 2) = kr1;
            *(bf16x8*)&Vs[srow][scol]      = v0;
            *(bf16x8*)&Vs[srow + 32][scol] = v1;
            if (t + 1 < ktiles) {   // issue next tile's loads now; complete
                const int kn = k0 + 64;  // during this tile's compute
                kc0 = *(const bf16x8*)&Kcg[(size_t)(kn + srow) * 64 + scol];
                kc1 = *(const bf16x8*)&Kcg[(size_t)(kn + srow + 32) * 64 + scol];
                kr0 = *(const bf16x8*)&Krg[(size_t)(kn + srow) * 64 + scol];
                kr1 = *(const bf16x8*)&Krg[(size_t)(kn + srow + 32) * 64 + scol];
                v0  = *(const bf16x8*)&Vg[(size_t)srow * S_ + kn + scol];
                v1  = *(const bf16x8*)&Vg[(size_t)(srow + 32) * S_ + kn + scol];
            }
            __syncthreads();   // LDS visible to all waves

            f32x4 sacc[4] = {};
            __builtin_amdgcn_s_setprio(1);
#pragma unroll
            for (int c = 0; c < 4; ++c) {
#pragma unroll
                for (int j = 0; j < 4; ++j) {
                    bf16x8 kb = *(const bf16x8*)KSP(n16 + 16 * j, c * 64 + quad * 16);
                    sacc[j] = mfma16(qf[c], kb, sacc[j]);
                }
            }
            __builtin_amdgcn_s_setprio(0);

            const bool boundary = (k0 + 63 > qbase);
#pragma unroll
            for (int j = 0; j < 4; ++j)
#pragma unroll
                for (int r = 0; r < 4; ++r) {
                    float s = sacc[j][r] * scale;
                    if (boundary && (k0 + 16 * j + n16 > qbase + quad * 4 + r))
                        s = -3e30f;
                    sacc[j][r] = s;
                }

            float alpha[4];
#pragma unroll
            for (int r = 0; r < 4; ++r) {
                float mx = fmaxf(fmaxf(sacc[0][r], sacc[1][r]),
                                 fmaxf(sacc[2][r], sacc[3][r]));
                mx = fmaxf(mx, __shfl_xor(mx, 1));
                mx = fmaxf(mx, __shfl_xor(mx, 2));
                mx = fmaxf(mx, __shfl_xor(mx, 4));
                mx = fmaxf(mx, __shfl_xor(mx, 8));
                const float mn = fmaxf(mrow[r], mx);
                alpha[r] = __expf(mrow[r] - mn);
                mrow[r] = mn;
                float rs = 0.f;
#pragma unroll
                for (int j = 0; j < 4; ++j) {
                    const float e = __expf(sacc[j][r] - mn);
                    sacc[j][r] = e;
                    rs += e;
                }
                rs += __shfl_xor(rs, 1);
                rs += __shfl_xor(rs, 2);
                rs += __shfl_xor(rs, 4);
                rs += __shfl_xor(rs, 8);
                lrow[r] = lrow[r] * alpha[r] + rs;
            }
#pragma unroll
            for (int nt = 0; nt < 4; ++nt)
#pragma unroll
                for (int r = 0; r < 4; ++r)
                    oacc[nt][r] *= alpha[r];

#pragma unroll
            for (int r = 0; r < 4; ++r)
#pragma unroll
                for (int j = 0; j < 4; ++j)
                    Ps[wave][quad * 4 + r][j * 16 + n16] = (bf16_t)sacc[j][r];

            __builtin_amdgcn_s_setprio(1);
#pragma unroll
            for (int hh = 0; hh < 2; ++hh) {
                bf16x8 pf = *(const bf16x8*)&Ps[wave][n16][hh * 32 + quad * 8];
#pragma unroll
                for (int nt = 0; nt < 4; ++nt) {
                    bf16x8 vb = *(const bf16x8*)&Vs[nt * 16 + n16][hh * 32 + quad * 8];
                    oacc[nt] = mfma16(pf, vb, oacc[nt]);
                }
            }
            __builtin_amdgcn_s_setprio(0);
        }

        float il[4];
#pragma unroll
        for (int r = 0; r < 4; ++r) il[r] = 1.0f / lrow[r];

        // transposed O-write: stage 16q x 64d per wave in Ps, then 32B/lane
        // writes (4 lanes cover a 128B-contiguous output row).
#pragma unroll
        for (int nt = 0; nt < 4; ++nt)
#pragma unroll
            for (int r = 0; r < 4; ++r)
                Ps[wave][quad * 4 + r][nt * 16 + n16] = (bf16_t)(oacc[nt][r] * il[r]);
        {
            const int q = qbase + n16;
            bf16x8 w0 = *(const bf16x8*)&Ps[wave][n16][quad * 16];
            bf16x8 w1 = *(const bf16x8*)&Ps[wave][n16][quad * 16 + 8];
            bf16_t* dst = O + ((size_t)b * S_ + q) * (size_t)(H_ * 64)
                            + h * 64 + quad * 16;
            *(bf16x8*)dst = w0;
            *(bf16x8*)(dst + 8) = w1;
        }
    }
}

// ---------------------------------------------------------------------------
extern "C" void kernel_launch(void* const* d_in, const int* in_sizes, int n_in,
                              void* d_out, int out_size, void* d_ws, size_t ws_size,
                              hipStream_t stream) {
    const float* X     = (const float*)d_in[0];
    const float* W_dkv = (const float*)d_in[2];
    const float* b_dkv = (const float*)d_in[3];
    const float* W_dq  = (const float*)d_in[4];
    const float* b_dq  = (const float*)d_in[5];
    const float* W_uk  = (const float*)d_in[6];
    const float* b_uk  = (const float*)d_in[7];
    const float* W_uv  = (const float*)d_in[8];
    const float* b_uv  = (const float*)d_in[9];
    const float* W_uq  = (const float*)d_in[10];
    const float* b_uq  = (const float*)d_in[11];
    const float* W_qr  = (const float*)d_in[12];
    const float* b_qr  = (const float*)d_in[13];
    const float* W_kr  = (const float*)d_in[14];
    const float* b_kr  = (const float*)d_in[15];
    const float* W_fc  = (const float*)d_in[16];
    const float* b_fc  = (const float*)d_in[17];
    float* out = (float*)d_out;

    char* w = (char*)d_ws;
    bf16_t* Xb    = (bf16_t*)(w);                 // 8192x2048    33,554,432 B
    bf16_t* Wtdkv = (bf16_t*)(w + 33554432);      // 512x2048 (Wtdq adjacent)
    bf16_t* Wtdq  = (bf16_t*)(w + 35651584);      // 512x2048
    bf16_t* Wtuk  = (bf16_t*)(w + 37748736);      // 1024x512 (Wtuv adjacent)
    bf16_t* Wtuv  = (bf16_t*)(w + 38797312);      // 1024x512
    bf16_t* Wtuq  = (bf16_t*)(w + 39845888);      // 1024x512 (Wtqr adjacent)
    bf16_t* Wtqr  = (bf16_t*)(w + 40894464);      // 1024x512
    bf16_t* Wtfc  = (bf16_t*)(w + 41943040);      // 2048x1024     4,194,304
    bf16_t* ckv   = (bf16_t*)(w + 46137344);      // 8192x512 (cq adjacent)
    bf16_t* cq    = (bf16_t*)(w + 54525952);      // 8192x512
    bf16_t* Qb    = (bf16_t*)(w + 62914560);      // (64,2048,128) 33,554,432
    bf16_t* Kc    = (bf16_t*)(w + 96468992);      // (64,2048,64)  16,777,216
    bf16_t* Kr    = (bf16_t*)(w + 113246208);     // (4,2048,64)    1,048,576
    bf16_t* Wtkr  = (bf16_t*)(w + 114294784);     // 64x2048          262,144
    bf16_t* Vt    = (bf16_t*)(w + 130023424);     // (64,64,2048)  16,777,216
    bf16_t* attnb = (bf16_t*)(w + 146800640);     // 8192x1024    16,777,216

    const dim3 blk(256);
    const dim3 blk2(512);
    // one-time casts / transposes
    cast_bf16<<<16384, blk, 0, stream>>>(X, Xb, 16777216);
    transpose_cast<<<dim3(16, 64), blk, 0, stream>>>(W_dkv, Wtdkv, 2048, 512);
    transpose_cast<<<dim3(16, 64), blk, 0, stream>>>(W_dq, Wtdq, 2048, 512);
    transpose_cast<<<dim3(32, 16), blk, 0, stream>>>(W_uk, Wtuk, 512, 1024);
    transpose_cast<<<dim3(32, 16), blk, 0, stream>>>(W_uv, Wtuv, 512, 1024);
    transpose_cast<<<dim3(32, 16), blk, 0, stream>>>(W_uq, Wtuq, 512, 1024);
    transpose_cast<<<dim3(32, 16), blk, 0, stream>>>(W_qr, Wtqr, 512, 1024);
    transpose_cast<<<dim3(64, 32), blk, 0, stream>>>(W_fc, Wtfc, 1024, 2048);
    transpose_cast<<<dim3(2, 64), blk, 0, stream>>>(W_kr, Wtkr, 2048, 64);
    // fused projections: 8-wave big-tile GEMMs, grid (m-blocks, n-blocks)
    // mg00: BM=128 (WM=4,MT=2), BN=256 (WN=2,NT=8) -> grid 64x4 = 256 = 1/CU
    mgemm2<0, 0, 4, 2, 2, 8><<<dim3(64, 4), blk2, 0, stream>>>(
        Xb, Wtdkv, b_dkv, b_dq, ckv, cq, MTOK, 1024, 2048, 512, 512);
    // mg43/mg12/mg55: BM=256 (WM=2,MT=8), BN=256 (WN=4,NT=4) -> 32x8 = 256
    mgemm2<4, 3, 2, 4, 8, 4><<<dim3(32, 8), blk2, 0, stream>>>(
        ckv, Wtuk, b_uk, b_uv, Kc, Vt, MTOK, 2048, 512, 1024, 0);
    mgemm2<1, 2, 2, 4, 8, 4><<<dim3(32, 8), blk2, 0, stream>>>(
        cq, Wtuq, b_uq, b_qr, Qb, Qb, MTOK, 2048, 512, 1024, 0);
    gemm_kr_mfma<<<dim3(128), blk, 0, stream>>>(Xb, Wtkr, b_kr, Kr);
    // attention + out-proj
    flash_mfma<<<dim3(16, 64), blk, 0, stream>>>(Qb, Kc, Kr, Vt, attnb);
    mgemm2<5, 5, 2, 4, 8, 4><<<dim3(32, 8), blk2, 0, stream>>>(
        attnb, Wtfc, b_fc, b_fc, out, out, MTOK, 2048, 1024, 2048, 2048);
}